// Round 7
// baseline (178.045 us; speedup 1.0000x reference)
//
#include <hip/hip_runtime.h>
#include <hip/hip_fp16.h>

// GCN 2-layer: out = A_hat @ relu(A_hat @ (X W1) + b1) W2 + b2
// A_hat = D^-1/2 (A+I) D^-1/2.
// R19 (on R18's 175.5 us; R18's launch_bounds was neutral -> occupancy not
// the gather limiter):
//   Gather inner loop de-serialized: the per-edge ds_bpermute broadcast
//   (lane l8 held csr word wb+l8, shfl'd per t) is replaced by UNIFORM
//   direct loads -- all 8 lanes of a group load csrw[base+t] at the same
//   address (1 line/group, L1-hot, address-independent of loaded data, so
//   hoistable + software-pipelined a block ahead). Removes ALL cross-lane
//   ops and their lgkmcnt stalls from the critical path. csr loads lose
//   the nontemporal flag (same-line reuse across t-steps wants L1).
// Everything else identical to R18 (bucketed build, prescaled rows,
// ushort csr, fused gemm2, nt out-stores).

#define P1_EDGES 4096
#define BSTRIDE 16384   // ebuf slots per bucket (fixed stride), ~2x avg fill

typedef float vfloat4 __attribute__((ext_vector_type(4)));  // native vec for nt-store

// ---- scatter edges by dst>>8 into fixed-stride ebuf regions; cursor from 0.
// ebuf[slot] = dst<<16 | src ----
__global__ void bucket_kernel(const int* __restrict__ src, const int* __restrict__ dst,
                              unsigned* __restrict__ cursor, unsigned* __restrict__ ebuf,
                              int e, int B) {
    __shared__ unsigned hist[256];
    __shared__ unsigned base[256];
    for (int i = threadIdx.x; i < B; i += 1024) hist[i] = 0;
    __syncthreads();
    int e0 = blockIdx.x * P1_EDGES;
    int tbase = e0 + (int)threadIdx.x * 4;
    int4 sv = make_int4(0, 0, 0, 0), dv = make_int4(0, 0, 0, 0);
    if (tbase + 3 < e) {                       // vectorized 16B edge reads
        sv = ((const int4*)(src + e0))[threadIdx.x];
        dv = ((const int4*)(dst + e0))[threadIdx.x];
    } else {                                   // tail block only
        if (tbase + 0 < e) { sv.x = src[tbase + 0]; dv.x = dst[tbase + 0]; }
        if (tbase + 1 < e) { sv.y = src[tbase + 1]; dv.y = dst[tbase + 1]; }
        if (tbase + 2 < e) { sv.z = src[tbase + 2]; dv.z = dst[tbase + 2]; }
    }
    unsigned bk[4], rk[4], pk[4];
    bool vk[4];
#pragma unroll
    for (int k = 0; k < 4; ++k) {
        int t = tbase + k;
        vk[k] = (t < e);
        bk[k] = 0; rk[k] = 0; pk[k] = 0;
        if (vk[k]) {
            unsigned s = (unsigned)(k == 0 ? sv.x : k == 1 ? sv.y : k == 2 ? sv.z : sv.w);
            unsigned d = (unsigned)(k == 0 ? dv.x : k == 1 ? dv.y : k == 2 ? dv.z : dv.w);
            unsigned b = d >> 8;
            bk[k] = b;
            rk[k] = atomicAdd(&hist[b], 1u);     // rank within (block,bucket)
            pk[k] = (d << 16) | s;               // n < 2^16: both fit
        }
    }
    __syncthreads();
    for (int i = threadIdx.x; i < B; i += 1024)
        base[i] = hist[i] ? atomicAdd(&cursor[i], hist[i]) : 0u;
    __syncthreads();
#pragma unroll
    for (int k = 0; k < 4; ++k)
        if (vk[k]) {
            unsigned slot = base[bk[k]] + rk[k];
            if (slot < (unsigned)BSTRIDE)                  // overflow drop-guard
                ebuf[(size_t)bk[k] * BSTRIDE + slot] = pk[k];
        }
}

// ---- fused per-bucket stats + fill. Phase 0: in-block scan of all cursor
// words -> this block's bstart (fence-free: kernel boundary orders it).
// Then: count -> local scan -> rpf/dinv -> re-read ebuf (L2-hot) ->
// csr[slot] = src (ushort) ----
__global__ void statsfill_kernel(const unsigned* __restrict__ ebuf,
                                 const unsigned* __restrict__ bcnt,
                                 unsigned* __restrict__ rpf, float* __restrict__ dinv,
                                 unsigned short* __restrict__ csr, int n, int e) {
    __shared__ unsigned pos[256];
    __shared__ unsigned sh[256];
    __shared__ unsigned rpl[256];
    __shared__ unsigned bs;        // bstart[b] = sum of bcnt[0..b)
    int b = blockIdx.x;
    int w0 = b << 8;
    int wlen = min(w0 + 256, n) - w0;
    // phase 0: global bucket-prefix for this block
    unsigned c0 = 0;
    if (threadIdx.x < 256) { c0 = bcnt[threadIdx.x]; sh[threadIdx.x] = c0; }
    __syncthreads();
    for (int off = 1; off < 256; off <<= 1) {
        unsigned t = 0;
        if (threadIdx.x < 256 && threadIdx.x >= (unsigned)off) t = sh[threadIdx.x - off];
        __syncthreads();
        if (threadIdx.x < 256) sh[threadIdx.x] += t;
        __syncthreads();
    }
    if (threadIdx.x == (unsigned)b) bs = sh[b] - c0;   // exclusive prefix at b
    if (threadIdx.x < 256) pos[threadIdx.x] = 0;
    __syncthreads();
    unsigned cnt = bcnt[b];
    const unsigned* eb = ebuf + (size_t)b * BSTRIDE;
    for (unsigned j = threadIdx.x; j < cnt; j += 1024)
        atomicAdd(&pos[(eb[j] >> 16) - w0], 1u);
    __syncthreads();
    unsigned v = 0;
    if (threadIdx.x < 256) { v = pos[threadIdx.x]; sh[threadIdx.x] = v; }
    __syncthreads();
    for (int off = 1; off < 256; off <<= 1) {
        unsigned t = 0;
        if (threadIdx.x < 256 && threadIdx.x >= (unsigned)off) t = sh[threadIdx.x - off];
        __syncthreads();
        if (threadIdx.x < 256) sh[threadIdx.x] += t;
        __syncthreads();
    }
    if (threadIdx.x < 256) {
        unsigned rp = bs + sh[threadIdx.x] - v;          // global base + excl scan
        rpl[threadIdx.x] = rp;
        if ((int)threadIdx.x < wlen) {
            rpf[w0 + threadIdx.x] = rp;
            dinv[w0 + threadIdx.x] = rsqrtf((float)v + 1.0f);   // +1 self-loop
        }
        pos[threadIdx.x] = 0;                            // reset for fill phase
    }
    if (b == (int)gridDim.x - 1 && threadIdx.x == 0) rpf[n] = (unsigned)e;
    __syncthreads();
    for (unsigned j = threadIdx.x; j < cnt; j += 1024) {
        unsigned p = eb[j];                              // L2-hot re-read
        unsigned d = (p >> 16) - w0;
        unsigned r = atomicAdd(&pos[d], 1u);
        csr[rpl[d] + r] = (unsigned short)(p & 0xffffu);
    }
}

// ---- Yh[n,64] (fp16) = dinv[row] * (X[n,64] @ W[64,64]); 16 lanes/row ----
__global__ void gemm64_kernel(const float4* __restrict__ X4, const float* __restrict__ W,
                              const float* __restrict__ dinv, __half* __restrict__ Yh, int n) {
    __shared__ float4 Ws[64][16];  // Ws[k][l] = W[k][4l..4l+3]
    for (int i = threadIdx.x; i < 64 * 16; i += blockDim.x)
        Ws[i >> 4][i & 15] = ((const float4*)W)[i];
    __syncthreads();
    int lane = threadIdx.x & 63;
    int l = lane & 15;
    int gbase = lane & 48;
    int wid = blockIdx.x * (blockDim.x >> 6) + (threadIdx.x >> 6);
    int row = wid * 4 + (lane >> 4);
    if (row >= n) return;
    float4 xv = X4[(size_t)row * 16 + l];
    float4 acc = make_float4(0.f, 0.f, 0.f, 0.f);
#pragma unroll
    for (int k = 0; k < 64; ++k) {
        float comp = (k & 3) == 0 ? xv.x : (k & 3) == 1 ? xv.y : (k & 3) == 2 ? xv.z : xv.w;
        float a = __shfl(comp, gbase + (k >> 2));
        float4 w = Ws[k][l];
        acc.x = fmaf(a, w.x, acc.x); acc.y = fmaf(a, w.y, acc.y);
        acc.z = fmaf(a, w.z, acc.z); acc.w = fmaf(a, w.w, acc.w);
    }
    float di = dinv[row];                    // row prescale (norm factorization)
    __half2 h0 = __floats2half2_rn(acc.x * di, acc.y * di);
    __half2 h1 = __floats2half2_rn(acc.z * di, acc.w * di);
    uint2 o;
    o.x = *(const unsigned*)&h0;
    o.y = *(const unsigned*)&h1;
    *(uint2*)(Yh + (size_t)row * 64 + 4 * l) = o;
}

// ---- aggregation core: 8-lane group per dst row; lane l8 owns cols
// 8*l8..8*l8+7. csr is ushort src-only; all 8 lanes of a group load each
// csr WORD at the same address (uniform -> 1 line, no cross-lane ops),
// double-buffered a block (8 words = 16 edges) ahead. Head/tail via 0/1
// weights. Rows are prescaled: plain sums. ----
struct f8 { float4 a, b; };

__device__ __forceinline__ f8 aggregate_row8(const __half* __restrict__ xwh,
                                             const unsigned* __restrict__ csrw,
                                             unsigned start, unsigned end,
                                             int row, int l8) {
    f8 acc;
    {   // self-loop term: xwh'[row] (prescaled) with weight 1
        uint4 hv = *(const uint4*)(xwh + (size_t)row * 64 + 8 * l8);
        float2 f0 = __half22float2(*(const __half2*)&hv.x);
        float2 f1 = __half22float2(*(const __half2*)&hv.y);
        float2 f2 = __half22float2(*(const __half2*)&hv.z);
        float2 f3 = __half22float2(*(const __half2*)&hv.w);
        acc.a = make_float4(f0.x, f0.y, f1.x, f1.y);
        acc.b = make_float4(f2.x, f2.y, f3.x, f3.y);
    }
    unsigned wb = start >> 1;              // first csr word
    unsigned we = (end + 1) >> 1;          // one past last word
    unsigned wnext[8];
#pragma unroll
    for (int t = 0; t < 8; ++t)
        wnext[t] = (wb + (unsigned)t < we) ? csrw[wb + t] : 0u;
    for (unsigned base = wb; base < we; base += 8) {
        unsigned w[8];
#pragma unroll
        for (int t = 0; t < 8; ++t) w[t] = wnext[t];
#pragma unroll
        for (int t = 0; t < 8; ++t)
            wnext[t] = (base + 8u + (unsigned)t < we) ? csrw[base + 8 + t] : 0u;
#pragma unroll
        for (int t = 0; t < 8; ++t) {
            unsigned p = w[t];
            unsigned i0 = (base + (unsigned)t) * 2;          // edge idx of lo half
            int s0 = (int)(p & 0xffffu);
            int s1 = (int)(p >> 16);
            float w0 = (i0 >= start && i0 < end) ? 1.0f : 0.0f;  // head+tail guard
            float w1 = (i0 + 1 < end) ? 1.0f : 0.0f;             // i0+1 >= start always
            uint4 hv0 = *(const uint4*)(xwh + (size_t)s0 * 64 + 8 * l8);
            uint4 hv1 = *(const uint4*)(xwh + (size_t)s1 * 64 + 8 * l8);
            float2 a0 = __half22float2(*(const __half2*)&hv0.x);
            float2 a1 = __half22float2(*(const __half2*)&hv0.y);
            float2 a2 = __half22float2(*(const __half2*)&hv0.z);
            float2 a3 = __half22float2(*(const __half2*)&hv0.w);
            acc.a.x = fmaf(w0, a0.x, acc.a.x); acc.a.y = fmaf(w0, a0.y, acc.a.y);
            acc.a.z = fmaf(w0, a1.x, acc.a.z); acc.a.w = fmaf(w0, a1.y, acc.a.w);
            acc.b.x = fmaf(w0, a2.x, acc.b.x); acc.b.y = fmaf(w0, a2.y, acc.b.y);
            acc.b.z = fmaf(w0, a3.x, acc.b.z); acc.b.w = fmaf(w0, a3.y, acc.b.w);
            float2 c0 = __half22float2(*(const __half2*)&hv1.x);
            float2 c1 = __half22float2(*(const __half2*)&hv1.y);
            float2 c2 = __half22float2(*(const __half2*)&hv1.z);
            float2 c3 = __half22float2(*(const __half2*)&hv1.w);
            acc.a.x = fmaf(w1, c0.x, acc.a.x); acc.a.y = fmaf(w1, c0.y, acc.a.y);
            acc.a.z = fmaf(w1, c1.x, acc.a.z); acc.a.w = fmaf(w1, c1.y, acc.a.w);
            acc.b.x = fmaf(w1, c2.x, acc.b.x); acc.b.y = fmaf(w1, c2.y, acc.b.y);
            acc.b.z = fmaf(w1, c3.x, acc.b.z); acc.b.w = fmaf(w1, c3.y, acc.b.w);
        }
    }
    return acc;
}

// ---- gather1 + fused gemm2: h = relu(di*agg + b1) (regs only);
// xwh2' = di * (h @ W2) -> fp16. di from row_ptr (deg = end-start). ----
__global__ void __launch_bounds__(256, 3)
gather_gemm_kernel(const __half* __restrict__ xwh, const unsigned* __restrict__ csrw,
                   const unsigned* __restrict__ row_ptr,
                   const float* __restrict__ b1, const float* __restrict__ W2,
                   __half* __restrict__ Yh, int n) {
    __shared__ float4 Ws[64][16];  // Ws[k][j] = W2[k][4j..4j+3]
    for (int i = threadIdx.x; i < 64 * 16; i += blockDim.x)
        Ws[i >> 4][i & 15] = ((const float4*)W2)[i];
    __syncthreads();
    int lane = threadIdx.x & 63;
    int l8 = lane & 7;
    int gbase = lane & 56;
    int wid = blockIdx.x * (blockDim.x >> 6) + (threadIdx.x >> 6);
    int row = wid * 8 + (lane >> 3);
    if (row >= n) return;  // whole 8-lane group exits together (after Ws sync)
    unsigned start = row_ptr[row], end = row_ptr[row + 1];
    float di = rsqrtf((float)(end - start) + 1.0f);
    f8 acc = aggregate_row8(xwh, csrw, start, end, row, l8);
    float4 ba = ((const float4*)b1)[2 * l8];
    float4 bb = ((const float4*)b1)[2 * l8 + 1];
    float h0 = fmaxf(fmaf(di, acc.a.x, ba.x), 0.f);
    float h1 = fmaxf(fmaf(di, acc.a.y, ba.y), 0.f);
    float h2 = fmaxf(fmaf(di, acc.a.z, ba.z), 0.f);
    float h3 = fmaxf(fmaf(di, acc.a.w, ba.w), 0.f);
    float h4 = fmaxf(fmaf(di, acc.b.x, bb.x), 0.f);
    float h5 = fmaxf(fmaf(di, acc.b.y, bb.y), 0.f);
    float h6 = fmaxf(fmaf(di, acc.b.z, bb.z), 0.f);
    float h7 = fmaxf(fmaf(di, acc.b.w, bb.w), 0.f);
    // fused gemm: out[8*l8 + c] = sum_k h[k] * W2[k][8*l8+c]
    float4 o0 = make_float4(0.f, 0.f, 0.f, 0.f);
    float4 o1 = make_float4(0.f, 0.f, 0.f, 0.f);
#pragma unroll
    for (int k = 0; k < 64; ++k) {
        float comp = (k & 7) == 0 ? h0 : (k & 7) == 1 ? h1 : (k & 7) == 2 ? h2 :
                     (k & 7) == 3 ? h3 : (k & 7) == 4 ? h4 : (k & 7) == 5 ? h5 :
                     (k & 7) == 6 ? h6 : h7;
        float a = __shfl(comp, gbase + (k >> 3));
        float4 w0 = Ws[k][2 * l8];
        float4 w1 = Ws[k][2 * l8 + 1];
        o0.x = fmaf(a, w0.x, o0.x); o0.y = fmaf(a, w0.y, o0.y);
        o0.z = fmaf(a, w0.z, o0.z); o0.w = fmaf(a, w0.w, o0.w);
        o1.x = fmaf(a, w1.x, o1.x); o1.y = fmaf(a, w1.y, o1.y);
        o1.z = fmaf(a, w1.z, o1.z); o1.w = fmaf(a, w1.w, o1.w);
    }
    __half2 p0 = __floats2half2_rn(o0.x * di, o0.y * di);   // layer-2 prescale
    __half2 p1 = __floats2half2_rn(o0.z * di, o0.w * di);
    __half2 p2 = __floats2half2_rn(o1.x * di, o1.y * di);
    __half2 p3 = __floats2half2_rn(o1.z * di, o1.w * di);
    uint4 o;
    o.x = *(const unsigned*)&p0; o.y = *(const unsigned*)&p1;
    o.z = *(const unsigned*)&p2; o.w = *(const unsigned*)&p3;
    *(uint4*)(Yh + (size_t)row * 64 + 8 * l8) = o;   // 128 B contiguous: full lines
}

// ---- gather2: out = di*agg + b2 -> fp32 out (nontemporal: write-once) ----
__global__ void __launch_bounds__(256, 3)
gather_out_kernel(const __half* __restrict__ xwh, const unsigned* __restrict__ csrw,
                  const unsigned* __restrict__ row_ptr,
                  const float* __restrict__ bias, float4* __restrict__ out4, int n) {
    int lane = threadIdx.x & 63;
    int l8 = lane & 7;
    int wid = blockIdx.x * (blockDim.x >> 6) + (threadIdx.x >> 6);
    int row = wid * 8 + (lane >> 3);
    if (row >= n) return;
    unsigned start = row_ptr[row], end = row_ptr[row + 1];
    float di = rsqrtf((float)(end - start) + 1.0f);
    f8 acc = aggregate_row8(xwh, csrw, start, end, row, l8);
    float4 ba = ((const float4*)bias)[2 * l8];
    float4 bb = ((const float4*)bias)[2 * l8 + 1];
    vfloat4 oa, ob;
    oa.x = fmaf(di, acc.a.x, ba.x); oa.y = fmaf(di, acc.a.y, ba.y);
    oa.z = fmaf(di, acc.a.z, ba.z); oa.w = fmaf(di, acc.a.w, ba.w);
    ob.x = fmaf(di, acc.b.x, bb.x); ob.y = fmaf(di, acc.b.y, bb.y);
    ob.z = fmaf(di, acc.b.z, bb.z); ob.w = fmaf(di, acc.b.w, bb.w);
    vfloat4* o4 = (vfloat4*)out4;
    __builtin_nontemporal_store(oa, &o4[(size_t)row * 16 + 2 * l8]);
    __builtin_nontemporal_store(ob, &o4[(size_t)row * 16 + 2 * l8 + 1]);
}

extern "C" void kernel_launch(void* const* d_in, const int* in_sizes, int n_in,
                              void* d_out, int out_size, void* d_ws, size_t ws_size,
                              hipStream_t stream) {
    const float* x  = (const float*)d_in[0];
    const int*   ei = (const int*)d_in[1];
    const float* W1 = (const float*)d_in[2];
    const float* b1 = (const float*)d_in[3];
    const float* W2 = (const float*)d_in[4];
    const float* b2 = (const float*)d_in[5];
    const int n = in_sizes[0] / 64;   // 50000 (packed paths require n <= 65535)
    const int e = in_sizes[1] / 2;    // 1600000
    const int* src = ei;              // edge_index[0]
    const int* dst = ei + e;          // edge_index[1]

    char* ws = (char*)d_ws;
    size_t off = 0;
    auto alloc = [&](size_t bytes) -> void* {
        void* p = ws + off;
        off = (off + bytes + 255) & ~(size_t)255;
        return p;
    };
    unsigned* rpf    = (unsigned*)alloc((size_t)(n + 1) * 4);
    float*    dinv   = (float*)alloc((size_t)n * 4);
    unsigned* cursor = (unsigned*)alloc(256 * 4);
    unsigned short* csr = (unsigned short*)alloc(((size_t)e / 2 + 64) * 4);  // 3.2 MB, word-padded
    const int B = (n + 255) / 256;                                   // 196 buckets
    // ebuf (fixed-stride, 196*16384*4 = 12.85 MB) dead after statsfill; overlay xwh1.
    size_t ebuf_sz = (size_t)B * BSTRIDE * 4;
    size_t ov = ebuf_sz > (size_t)n * 64 * 2 ? ebuf_sz : (size_t)n * 64 * 2;
    char*     overlay = (char*)alloc(ov);
    unsigned* ebuf    = (unsigned*)overlay;
    __half*   xwh1    = (__half*)overlay;
    __half*   xwh2    = (__half*)alloc((size_t)n * 64 * 2);          // 6.4 MB
    float*    outf    = (float*)d_out;

    const int nbP1 = (e + P1_EDGES - 1) / P1_EDGES;   // 391

    // CSR build (shared by both layers): bucket -> statsfill (self-scan, fence-free)
    hipMemsetAsync(cursor, 0, 256 * 4, stream);
    bucket_kernel<<<nbP1, 1024, 0, stream>>>(src, dst, cursor, ebuf, e, B);
    statsfill_kernel<<<B, 1024, 0, stream>>>(ebuf, cursor, rpf, dinv, csr, n, e);

    const int gblk16 = (n + 15) / 16;   // gemm: 4 rows/wave
    const int gblk32 = (n + 31) / 32;   // gathers: 8 rows/wave

    // layer 1 (+fused layer-2 gemm): xwh1 = fp16(dinv*(x@W1));
    // xwh2 = fp16(dinv * (relu(dinv*agg(xwh1) + b1) @ W2))
    gemm64_kernel<<<gblk16, 256, 0, stream>>>((const float4*)x, W1, dinv, xwh1, n);
    gather_gemm_kernel<<<gblk32, 256, 0, stream>>>(xwh1, (const unsigned*)csr, rpf, b1, W2, xwh2, n);

    // layer 2 aggregate: out = dinv*agg(xwh2) + b2
    gather_out_kernel<<<gblk32, 256, 0, stream>>>(xwh2, (const unsigned*)csr, rpf, b2, (float4*)outf, n);
}

// Round 8
// 170.790 us; speedup vs baseline: 1.0425x; 1.0425x over previous
//
#include <hip/hip_runtime.h>
#include <hip/hip_fp16.h>

// GCN 2-layer: out = A_hat @ relu(A_hat @ (X W1) + b1) W2 + b2
// A_hat = D^-1/2 (A+I) D^-1/2.
// R20 (on R18's 175.5 us; R19 shfl-removal neutral-negative -> REVERTED to
// R18 aggregate core. Gathers declared at L2/L3 random-service floor):
//   (1) gemm64 fused into bucket's LAUNCH (grid-partitioned mega-kernel):
//       blocks [0,nbP1) bucket, rest gemm @1024 thr. They are data-
//       independent -> run concurrently on one stream. gemm writes
//       UNSCALED fp16 xw1 (dinv unknown until statsfill).
//   (2) statsfill scales its 256-row xwh1 slab in place by dinv (dl in
//       LDS, 32 KB sequential per block) -- dinv global array deleted.
//   (3) xwh1 un-overlayed from ebuf (now concurrent); ws ~29 MB.
// Everything else identical to R18 (bucketed build, ushort csr, fused
// gemm2 in gather1, nt out-stores, launch_bounds on gathers).

#define P1_EDGES 4096
#define BSTRIDE 16384   // ebuf slots per bucket (fixed stride), ~2x avg fill

typedef float vfloat4 __attribute__((ext_vector_type(4)));  // native vec for nt-store

// ---- mega kernel: blocks [0,nbP1) = edge bucketing; blocks [nbP1, ...) =
// xw1 = fp16(X @ W1) UNSCALED (16 waves, 4 rows/wave, 64 rows/block) ----
__global__ void bucket_gemm_kernel(const int* __restrict__ src, const int* __restrict__ dst,
                                   unsigned* __restrict__ cursor, unsigned* __restrict__ ebuf,
                                   const float4* __restrict__ X4, const float* __restrict__ W,
                                   __half* __restrict__ Yh,
                                   int e, int B, int n, int nbP1) {
    __shared__ unsigned hist[256];
    __shared__ unsigned base[256];
    __shared__ float4 Ws[64][16];
    int bid = blockIdx.x;
    if (bid < nbP1) {
        // ---- bucket branch: scatter edges by dst>>8; ebuf[slot]=dst<<16|src ----
        for (int i = threadIdx.x; i < B; i += 1024) hist[i] = 0;
        __syncthreads();
        int e0 = bid * P1_EDGES;
        int tbase = e0 + (int)threadIdx.x * 4;
        int4 sv = make_int4(0, 0, 0, 0), dv = make_int4(0, 0, 0, 0);
        if (tbase + 3 < e) {                       // vectorized 16B edge reads
            sv = ((const int4*)(src + e0))[threadIdx.x];
            dv = ((const int4*)(dst + e0))[threadIdx.x];
        } else {                                   // tail block only
            if (tbase + 0 < e) { sv.x = src[tbase + 0]; dv.x = dst[tbase + 0]; }
            if (tbase + 1 < e) { sv.y = src[tbase + 1]; dv.y = dst[tbase + 1]; }
            if (tbase + 2 < e) { sv.z = src[tbase + 2]; dv.z = dst[tbase + 2]; }
        }
        unsigned bk[4], rk[4], pk[4];
        bool vk[4];
#pragma unroll
        for (int k = 0; k < 4; ++k) {
            int t = tbase + k;
            vk[k] = (t < e);
            bk[k] = 0; rk[k] = 0; pk[k] = 0;
            if (vk[k]) {
                unsigned s = (unsigned)(k == 0 ? sv.x : k == 1 ? sv.y : k == 2 ? sv.z : sv.w);
                unsigned d = (unsigned)(k == 0 ? dv.x : k == 1 ? dv.y : k == 2 ? dv.z : dv.w);
                unsigned b = d >> 8;
                bk[k] = b;
                rk[k] = atomicAdd(&hist[b], 1u);     // rank within (block,bucket)
                pk[k] = (d << 16) | s;               // n < 2^16: both fit
            }
        }
        __syncthreads();
        for (int i = threadIdx.x; i < B; i += 1024)
            base[i] = hist[i] ? atomicAdd(&cursor[i], hist[i]) : 0u;
        __syncthreads();
#pragma unroll
        for (int k = 0; k < 4; ++k)
            if (vk[k]) {
                unsigned slot = base[bk[k]] + rk[k];
                if (slot < (unsigned)BSTRIDE)                  // overflow drop-guard
                    ebuf[(size_t)bk[k] * BSTRIDE + slot] = pk[k];
            }
    } else {
        // ---- gemm branch: Yh[row] = fp16(X[row] @ W) (no prescale) ----
        for (int i = threadIdx.x; i < 64 * 16; i += 1024)
            Ws[i >> 4][i & 15] = ((const float4*)W)[i];
        __syncthreads();
        int lane = threadIdx.x & 63;
        int l = lane & 15;
        int gbase = lane & 48;
        int wid = (bid - nbP1) * 16 + (threadIdx.x >> 6);
        int row = wid * 4 + (lane >> 4);
        if (row >= n) return;
        float4 xv = X4[(size_t)row * 16 + l];
        float4 acc = make_float4(0.f, 0.f, 0.f, 0.f);
#pragma unroll
        for (int k = 0; k < 64; ++k) {
            float comp = (k & 3) == 0 ? xv.x : (k & 3) == 1 ? xv.y : (k & 3) == 2 ? xv.z : xv.w;
            float a = __shfl(comp, gbase + (k >> 2));
            float4 w = Ws[k][l];
            acc.x = fmaf(a, w.x, acc.x); acc.y = fmaf(a, w.y, acc.y);
            acc.z = fmaf(a, w.z, acc.z); acc.w = fmaf(a, w.w, acc.w);
        }
        __half2 h0 = __floats2half2_rn(acc.x, acc.y);
        __half2 h1 = __floats2half2_rn(acc.z, acc.w);
        uint2 o;
        o.x = *(const unsigned*)&h0;
        o.y = *(const unsigned*)&h1;
        *(uint2*)(Yh + (size_t)row * 64 + 4 * l) = o;
    }
}

// ---- fused per-bucket stats + fill + xwh1 scale. Phase 0: in-block scan
// of cursor -> bstart (fence-free). Then: count -> local scan -> rpf ->
// scale xwh1 window rows by dinv (in place) -> re-read ebuf (L2-hot) ->
// csr[slot] = src (ushort) ----
__global__ void statsfill_kernel(const unsigned* __restrict__ ebuf,
                                 const unsigned* __restrict__ bcnt,
                                 unsigned* __restrict__ rpf,
                                 __half* __restrict__ xwh1,
                                 unsigned short* __restrict__ csr, int n, int e) {
    __shared__ unsigned pos[256];
    __shared__ unsigned sh[256];
    __shared__ unsigned rpl[256];
    __shared__ float dl[256];
    __shared__ unsigned bs;        // bstart[b] = sum of bcnt[0..b)
    int b = blockIdx.x;
    int w0 = b << 8;
    int wlen = min(w0 + 256, n) - w0;
    // phase 0: global bucket-prefix for this block
    unsigned c0 = 0;
    if (threadIdx.x < 256) { c0 = bcnt[threadIdx.x]; sh[threadIdx.x] = c0; }
    __syncthreads();
    for (int off = 1; off < 256; off <<= 1) {
        unsigned t = 0;
        if (threadIdx.x < 256 && threadIdx.x >= (unsigned)off) t = sh[threadIdx.x - off];
        __syncthreads();
        if (threadIdx.x < 256) sh[threadIdx.x] += t;
        __syncthreads();
    }
    if (threadIdx.x == (unsigned)b) bs = sh[b] - c0;   // exclusive prefix at b
    if (threadIdx.x < 256) pos[threadIdx.x] = 0;
    __syncthreads();
    unsigned cnt = bcnt[b];
    const unsigned* eb = ebuf + (size_t)b * BSTRIDE;
    for (unsigned j = threadIdx.x; j < cnt; j += 1024)
        atomicAdd(&pos[(eb[j] >> 16) - w0], 1u);
    __syncthreads();
    unsigned v = 0;
    if (threadIdx.x < 256) { v = pos[threadIdx.x]; sh[threadIdx.x] = v; }
    __syncthreads();
    for (int off = 1; off < 256; off <<= 1) {
        unsigned t = 0;
        if (threadIdx.x < 256 && threadIdx.x >= (unsigned)off) t = sh[threadIdx.x - off];
        __syncthreads();
        if (threadIdx.x < 256) sh[threadIdx.x] += t;
        __syncthreads();
    }
    if (threadIdx.x < 256) {
        unsigned rp = bs + sh[threadIdx.x] - v;          // global base + excl scan
        rpl[threadIdx.x] = rp;
        dl[threadIdx.x] = rsqrtf((float)v + 1.0f);       // +1 self-loop
        if ((int)threadIdx.x < wlen) rpf[w0 + threadIdx.x] = rp;
        pos[threadIdx.x] = 0;                            // reset for fill phase
    }
    if (b == (int)gridDim.x - 1 && threadIdx.x == 0) rpf[n] = (unsigned)e;
    __syncthreads();
    // phase S: scale xwh1 rows [w0, w0+wlen) by dinv, in place.
    // 8 chunks of 16 B per row; 1024 threads cover 2048 chunks in 2 steps.
    for (int i = threadIdx.x; i < (wlen << 3); i += 1024) {
        int r = i >> 3, c = i & 7;
        float di = dl[r];
        uint4* p16 = (uint4*)(xwh1 + ((size_t)(w0 + r) << 6)) + c;
        uint4 hv = *p16;
        float2 f0 = __half22float2(*(const __half2*)&hv.x);
        float2 f1 = __half22float2(*(const __half2*)&hv.y);
        float2 f2 = __half22float2(*(const __half2*)&hv.z);
        float2 f3 = __half22float2(*(const __half2*)&hv.w);
        __half2 g0 = __floats2half2_rn(f0.x * di, f0.y * di);
        __half2 g1 = __floats2half2_rn(f1.x * di, f1.y * di);
        __half2 g2 = __floats2half2_rn(f2.x * di, f2.y * di);
        __half2 g3 = __floats2half2_rn(f3.x * di, f3.y * di);
        hv.x = *(const unsigned*)&g0; hv.y = *(const unsigned*)&g1;
        hv.z = *(const unsigned*)&g2; hv.w = *(const unsigned*)&g3;
        *p16 = hv;
    }
    // phase F: fill csr
    for (unsigned j = threadIdx.x; j < cnt; j += 1024) {
        unsigned p = eb[j];                              // L2-hot re-read
        unsigned d = (p >> 16) - w0;
        unsigned r = atomicAdd(&pos[d], 1u);
        csr[rpl[d] + r] = (unsigned short)(p & 0xffffu);
    }
}

// ---- aggregation core (R18 form): 8-lane group per dst row; lane l8 owns
// cols 8*l8..8*l8+7. csr ushort read as uint words (2 edges/word) via lane
// l8 + shfl broadcast; head/tail via 0/1 weights. Rows prescaled. ----
struct f8 { float4 a, b; };

__device__ __forceinline__ f8 aggregate_row8(const __half* __restrict__ xwh,
                                             const unsigned* __restrict__ csrw,
                                             unsigned start, unsigned end,
                                             int row, int l8, int gbase) {
    f8 acc;
    {   // self-loop term: xwh'[row] (prescaled) with weight 1
        uint4 hv = *(const uint4*)(xwh + (size_t)row * 64 + 8 * l8);
        float2 f0 = __half22float2(*(const __half2*)&hv.x);
        float2 f1 = __half22float2(*(const __half2*)&hv.y);
        float2 f2 = __half22float2(*(const __half2*)&hv.z);
        float2 f3 = __half22float2(*(const __half2*)&hv.w);
        acc.a = make_float4(f0.x, f0.y, f1.x, f1.y);
        acc.b = make_float4(f2.x, f2.y, f3.x, f3.y);
    }
    unsigned wb = start >> 1;                        // first csr word
    unsigned jw = wb + (unsigned)l8;
    unsigned ed = (jw * 2 < end) ? __builtin_nontemporal_load(&csrw[jw]) : 0u;
    for (unsigned base = wb; base * 2 < end; base += 8) {
        unsigned jn = base + 8 + (unsigned)l8;
        unsigned ed_next = (jn * 2 < end) ? __builtin_nontemporal_load(&csrw[jn]) : 0u;
#pragma unroll
        for (int t = 0; t < 8; ++t) {
            unsigned p = __shfl(ed, gbase + t);
            unsigned i0 = (base + (unsigned)t) * 2;          // edge idx of lo half
            int s0 = (int)(p & 0xffffu);
            int s1 = (int)(p >> 16);
            float w0 = (i0 >= start && i0 < end) ? 1.0f : 0.0f;  // head+tail guard
            float w1 = (i0 + 1 < end) ? 1.0f : 0.0f;             // i0+1 >= start always
            uint4 hv0 = *(const uint4*)(xwh + (size_t)s0 * 64 + 8 * l8);
            uint4 hv1 = *(const uint4*)(xwh + (size_t)s1 * 64 + 8 * l8);
            float2 a0 = __half22float2(*(const __half2*)&hv0.x);
            float2 a1 = __half22float2(*(const __half2*)&hv0.y);
            float2 a2 = __half22float2(*(const __half2*)&hv0.z);
            float2 a3 = __half22float2(*(const __half2*)&hv0.w);
            acc.a.x = fmaf(w0, a0.x, acc.a.x); acc.a.y = fmaf(w0, a0.y, acc.a.y);
            acc.a.z = fmaf(w0, a1.x, acc.a.z); acc.a.w = fmaf(w0, a1.y, acc.a.w);
            acc.b.x = fmaf(w0, a2.x, acc.b.x); acc.b.y = fmaf(w0, a2.y, acc.b.y);
            acc.b.z = fmaf(w0, a3.x, acc.b.z); acc.b.w = fmaf(w0, a3.y, acc.b.w);
            float2 c0 = __half22float2(*(const __half2*)&hv1.x);
            float2 c1 = __half22float2(*(const __half2*)&hv1.y);
            float2 c2 = __half22float2(*(const __half2*)&hv1.z);
            float2 c3 = __half22float2(*(const __half2*)&hv1.w);
            acc.a.x = fmaf(w1, c0.x, acc.a.x); acc.a.y = fmaf(w1, c0.y, acc.a.y);
            acc.a.z = fmaf(w1, c1.x, acc.a.z); acc.a.w = fmaf(w1, c1.y, acc.a.w);
            acc.b.x = fmaf(w1, c2.x, acc.b.x); acc.b.y = fmaf(w1, c2.y, acc.b.y);
            acc.b.z = fmaf(w1, c3.x, acc.b.z); acc.b.w = fmaf(w1, c3.y, acc.b.w);
        }
        ed = ed_next;
    }
    return acc;
}

// ---- gather1 + fused gemm2: h = relu(di*agg + b1) (regs only);
// xwh2' = di * (h @ W2) -> fp16. di from row_ptr (deg = end-start). ----
__global__ void __launch_bounds__(256, 3)
gather_gemm_kernel(const __half* __restrict__ xwh, const unsigned* __restrict__ csrw,
                   const unsigned* __restrict__ row_ptr,
                   const float* __restrict__ b1, const float* __restrict__ W2,
                   __half* __restrict__ Yh, int n) {
    __shared__ float4 Ws[64][16];  // Ws[k][j] = W2[k][4j..4j+3]
    for (int i = threadIdx.x; i < 64 * 16; i += blockDim.x)
        Ws[i >> 4][i & 15] = ((const float4*)W2)[i];
    __syncthreads();
    int lane = threadIdx.x & 63;
    int l8 = lane & 7;
    int gbase = lane & 56;
    int wid = blockIdx.x * (blockDim.x >> 6) + (threadIdx.x >> 6);
    int row = wid * 8 + (lane >> 3);
    if (row >= n) return;  // whole 8-lane group exits together (after Ws sync)
    unsigned start = row_ptr[row], end = row_ptr[row + 1];
    float di = rsqrtf((float)(end - start) + 1.0f);
    f8 acc = aggregate_row8(xwh, csrw, start, end, row, l8, gbase);
    float4 ba = ((const float4*)b1)[2 * l8];
    float4 bb = ((const float4*)b1)[2 * l8 + 1];
    float h0 = fmaxf(fmaf(di, acc.a.x, ba.x), 0.f);
    float h1 = fmaxf(fmaf(di, acc.a.y, ba.y), 0.f);
    float h2 = fmaxf(fmaf(di, acc.a.z, ba.z), 0.f);
    float h3 = fmaxf(fmaf(di, acc.a.w, ba.w), 0.f);
    float h4 = fmaxf(fmaf(di, acc.b.x, bb.x), 0.f);
    float h5 = fmaxf(fmaf(di, acc.b.y, bb.y), 0.f);
    float h6 = fmaxf(fmaf(di, acc.b.z, bb.z), 0.f);
    float h7 = fmaxf(fmaf(di, acc.b.w, bb.w), 0.f);
    // fused gemm: out[8*l8 + c] = sum_k h[k] * W2[k][8*l8+c]
    float4 o0 = make_float4(0.f, 0.f, 0.f, 0.f);
    float4 o1 = make_float4(0.f, 0.f, 0.f, 0.f);
#pragma unroll
    for (int k = 0; k < 64; ++k) {
        float comp = (k & 7) == 0 ? h0 : (k & 7) == 1 ? h1 : (k & 7) == 2 ? h2 :
                     (k & 7) == 3 ? h3 : (k & 7) == 4 ? h4 : (k & 7) == 5 ? h5 :
                     (k & 7) == 6 ? h6 : h7;
        float a = __shfl(comp, gbase + (k >> 3));
        float4 w0 = Ws[k][2 * l8];
        float4 w1 = Ws[k][2 * l8 + 1];
        o0.x = fmaf(a, w0.x, o0.x); o0.y = fmaf(a, w0.y, o0.y);
        o0.z = fmaf(a, w0.z, o0.z); o0.w = fmaf(a, w0.w, o0.w);
        o1.x = fmaf(a, w1.x, o1.x); o1.y = fmaf(a, w1.y, o1.y);
        o1.z = fmaf(a, w1.z, o1.z); o1.w = fmaf(a, w1.w, o1.w);
    }
    __half2 p0 = __floats2half2_rn(o0.x * di, o0.y * di);   // layer-2 prescale
    __half2 p1 = __floats2half2_rn(o0.z * di, o0.w * di);
    __half2 p2 = __floats2half2_rn(o1.x * di, o1.y * di);
    __half2 p3 = __floats2half2_rn(o1.z * di, o1.w * di);
    uint4 o;
    o.x = *(const unsigned*)&p0; o.y = *(const unsigned*)&p1;
    o.z = *(const unsigned*)&p2; o.w = *(const unsigned*)&p3;
    *(uint4*)(Yh + (size_t)row * 64 + 8 * l8) = o;   // 128 B contiguous: full lines
}

// ---- gather2: out = di*agg + b2 -> fp32 out (nontemporal: write-once) ----
__global__ void __launch_bounds__(256, 3)
gather_out_kernel(const __half* __restrict__ xwh, const unsigned* __restrict__ csrw,
                  const unsigned* __restrict__ row_ptr,
                  const float* __restrict__ bias, float4* __restrict__ out4, int n) {
    int lane = threadIdx.x & 63;
    int l8 = lane & 7;
    int gbase = lane & 56;
    int wid = blockIdx.x * (blockDim.x >> 6) + (threadIdx.x >> 6);
    int row = wid * 8 + (lane >> 3);
    if (row >= n) return;
    unsigned start = row_ptr[row], end = row_ptr[row + 1];
    float di = rsqrtf((float)(end - start) + 1.0f);
    f8 acc = aggregate_row8(xwh, csrw, start, end, row, l8, gbase);
    float4 ba = ((const float4*)bias)[2 * l8];
    float4 bb = ((const float4*)bias)[2 * l8 + 1];
    vfloat4 oa, ob;
    oa.x = fmaf(di, acc.a.x, ba.x); oa.y = fmaf(di, acc.a.y, ba.y);
    oa.z = fmaf(di, acc.a.z, ba.z); oa.w = fmaf(di, acc.a.w, ba.w);
    ob.x = fmaf(di, acc.b.x, bb.x); ob.y = fmaf(di, acc.b.y, bb.y);
    ob.z = fmaf(di, acc.b.z, bb.z); ob.w = fmaf(di, acc.b.w, bb.w);
    vfloat4* o4 = (vfloat4*)out4;
    __builtin_nontemporal_store(oa, &o4[(size_t)row * 16 + 2 * l8]);
    __builtin_nontemporal_store(ob, &o4[(size_t)row * 16 + 2 * l8 + 1]);
}

extern "C" void kernel_launch(void* const* d_in, const int* in_sizes, int n_in,
                              void* d_out, int out_size, void* d_ws, size_t ws_size,
                              hipStream_t stream) {
    const float* x  = (const float*)d_in[0];
    const int*   ei = (const int*)d_in[1];
    const float* W1 = (const float*)d_in[2];
    const float* b1 = (const float*)d_in[3];
    const float* W2 = (const float*)d_in[4];
    const float* b2 = (const float*)d_in[5];
    const int n = in_sizes[0] / 64;   // 50000 (packed paths require n <= 65535)
    const int e = in_sizes[1] / 2;    // 1600000
    const int* src = ei;              // edge_index[0]
    const int* dst = ei + e;          // edge_index[1]

    char* ws = (char*)d_ws;
    size_t off = 0;
    auto alloc = [&](size_t bytes) -> void* {
        void* p = ws + off;
        off = (off + bytes + 255) & ~(size_t)255;
        return p;
    };
    unsigned* rpf    = (unsigned*)alloc((size_t)(n + 1) * 4);
    unsigned* cursor = (unsigned*)alloc(256 * 4);
    unsigned short* csr = (unsigned short*)alloc(((size_t)e / 2 + 64) * 4);  // 3.2 MB, word-padded
    const int B = (n + 255) / 256;                                   // 196 buckets
    unsigned* ebuf   = (unsigned*)alloc((size_t)B * BSTRIDE * 4);    // 12.85 MB (no overlay:
    __half*   xwh1   = (__half*)alloc((size_t)n * 64 * 2);           // concurrent with gemm)
    __half*   xwh2   = (__half*)alloc((size_t)n * 64 * 2);           // 6.4 MB
    float*    outf   = (float*)d_out;

    const int nbP1 = (e + P1_EDGES - 1) / P1_EDGES;   // 391 bucket blocks
    const int gblk64 = (n + 63) / 64;                 // 782 gemm blocks (64 rows each)

    // {bucket || gemm-unscaled} -> statsfill(+dinv-scale) -> gathers
    hipMemsetAsync(cursor, 0, 256 * 4, stream);
    bucket_gemm_kernel<<<nbP1 + gblk64, 1024, 0, stream>>>(
        src, dst, cursor, ebuf, (const float4*)x, W1, xwh1, e, B, n, nbP1);
    statsfill_kernel<<<B, 1024, 0, stream>>>(ebuf, cursor, rpf, xwh1, csr, n, e);

    const int gblk32 = (n + 31) / 32;   // gathers: 8 rows/wave

    // layer 1 (+fused layer-2 gemm), then layer 2 aggregate
    gather_gemm_kernel<<<gblk32, 256, 0, stream>>>(xwh1, (const unsigned*)csr, rpf, b1, W2, xwh2, n);
    gather_out_kernel<<<gblk32, 256, 0, stream>>>(xwh2, (const unsigned*)csr, rpf, b2, (float4*)outf, n);
}